// Round 1
// 13913.507 us; speedup vs baseline: 1.1946x; 1.1946x over previous
//
#include <hip/hip_runtime.h>
#include <stdint.h>

// LSTM: SEQ=2048, B=64, I=512, H=512, gates 4H=2048 in torch order i,f,g,o.
// Phase 1: x_proj[g][s*64+b] = W_ih[g,:].X[s,b,:] + b_ih[g]+b_hh[g]  (bf16 MFMA GEMM)
// Phase 2: persistent 32-block kernel, W_hh in VGPRs, c in registers.
//   h broadcast via relaxed AGENT-scope atomic ld/st (L1/L2-bypass, coherence-point
//   acked) -> NO buffer_wbl2 / buffer_inv cache maintenance anywhere in the loop.
//   Arrival: per-block flag store (32B apart) + relaxed vector poll of all 32 flags.
//   Release = s_waitcnt vmcnt(16): oldest-first retirement drains the 2 stores,
//   leaves the 16 xp prefetch loads (issued for t+1 BEFORE the wait) in flight.

typedef __bf16 bf16;
typedef __bf16 bf16x4 __attribute__((ext_vector_type(4)));
typedef __bf16 bf16x8 __attribute__((ext_vector_type(8)));
typedef float  f32x4  __attribute__((ext_vector_type(4)));
typedef unsigned long long u64;

#define SEQN  2048
#define BATCH 64
#define IDIM  512
#define HDIM  512
#define GDIM  2048
#define NTOT  131072   // SEQ*BATCH
#define NBLK  32

// workspace layout (bytes)
#define CNT_OFF  0u                           // 32 arrival flags, 32B apart (1 KB)
#define H0_OFF   1024u
#define H1_OFF   (H0_OFF + 65536u)
#define BIAS_OFF (H1_OFF + 65536u)            // fp32[2048]
#define WIH_OFF  (BIAS_OFF + 8192u)           // bf16 [2048][512]
#define WHH_OFF  (WIH_OFF + 2097152u)         // bf16 [2048][512]
#define XBF_OFF  (WHH_OFF + 2097152u)         // bf16 [131072][512]
#define XP_OFF   (XBF_OFF + 134217728u)       // bf16 [2048][131072]  (512 MB)

__device__ __forceinline__ float sigf(float x)     { return 1.0f / (1.0f + __expf(-x)); }
__device__ __forceinline__ float tanhfast(float x) { return 2.0f / (1.0f + __expf(-2.0f * x)) - 1.0f; }

// ---- init: zero flags + h double buffers, bias = b_ih + b_hh ----
__global__ void k_init(const float* __restrict__ bih, const float* __restrict__ bhh,
                       float* __restrict__ bias, uint32_t* __restrict__ zbase, int zwords) {
    int i = blockIdx.x * blockDim.x + threadIdx.x;
    int stride = gridDim.x * blockDim.x;
    for (int j = i; j < zwords; j += stride) zbase[j] = 0u;
    for (int j = i; j < GDIM;   j += stride) bias[j] = bih[j] + bhh[j];
}

// ---- fp32 -> bf16 convert (vectorized 4-wide) ----
__global__ void k_cvt(const float* __restrict__ in, bf16* __restrict__ out, int n4) {
    int stride = gridDim.x * blockDim.x;
    for (int j = blockIdx.x * blockDim.x + threadIdx.x; j < n4; j += stride) {
        float4 v = ((const float4*)in)[j];
        bf16x4 o;
        o[0] = (bf16)v.x; o[1] = (bf16)v.y; o[2] = (bf16)v.z; o[3] = (bf16)v.w;
        *((bf16x4*)out + j) = o;
    }
}

// ---- phase 1 GEMM: C[g][n] = sum_k W[g][k] * X[n][k] + bias[g], stored bf16 ----
__global__ __launch_bounds__(256) void k_gemm_xproj(const bf16* __restrict__ Wb,
                                                    const bf16* __restrict__ Xb,
                                                    const float* __restrict__ bias,
                                                    bf16* __restrict__ xp) {
    __shared__ bf16 As[128 * 72];
    __shared__ bf16 Bs[128 * 72];
    const int tid = threadIdx.x;
    const int bm = blockIdx.x, bn = blockIdx.y;
    const int w = tid >> 6, lane = tid & 63;
    const int l15 = lane & 15, quad = lane >> 4;
    const int mh = (w >> 1) << 6, nh = (w & 1) << 6;

    f32x4 acc[4][4];
#pragma unroll
    for (int i = 0; i < 4; ++i)
#pragma unroll
        for (int j = 0; j < 4; ++j) { f32x4 z = {0.f, 0.f, 0.f, 0.f}; acc[i][j] = z; }

    for (int kk = 0; kk < 512; kk += 64) {
#pragma unroll
        for (int it = 0; it < 4; ++it) {
            int off  = it * 4096 + tid * 16;
            int row  = off >> 7;
            int colh = (off & 127) >> 1;
            *(bf16x8*)(&As[row * 72 + colh]) =
                *(const bf16x8*)(Wb + (size_t)(bm * 128 + row) * 512 + kk + colh);
            *(bf16x8*)(&Bs[row * 72 + colh]) =
                *(const bf16x8*)(Xb + (size_t)(bn * 128 + row) * 512 + kk + colh);
        }
        __syncthreads();
#pragma unroll
        for (int ks = 0; ks < 2; ++ks) {
            bf16x8 af[4], bfm[4];
#pragma unroll
            for (int mt = 0; mt < 4; ++mt)
                af[mt]  = *(const bf16x8*)(&As[(mh + mt * 16 + l15) * 72 + ks * 32 + quad * 8]);
#pragma unroll
            for (int nt = 0; nt < 4; ++nt)
                bfm[nt] = *(const bf16x8*)(&Bs[(nh + nt * 16 + l15) * 72 + ks * 32 + quad * 8]);
#pragma unroll
            for (int mt = 0; mt < 4; ++mt)
#pragma unroll
                for (int nt = 0; nt < 4; ++nt)
                    acc[mt][nt] = __builtin_amdgcn_mfma_f32_16x16x32_bf16(af[mt], bfm[nt], acc[mt][nt], 0, 0, 0);
        }
        __syncthreads();
    }

#pragma unroll
    for (int mt = 0; mt < 4; ++mt)
#pragma unroll
        for (int r = 0; r < 4; ++r) {
            int g = bm * 128 + mh + mt * 16 + quad * 4 + r;
            float bv = bias[g];
#pragma unroll
            for (int nt = 0; nt < 4; ++nt) {
                int n = bn * 128 + nh + nt * 16 + l15;
                xp[(size_t)g * NTOT + n] = (bf16)(acc[mt][nt][r] + bv);
            }
        }
}

// ---- phase 2: persistent recurrence. 32 blocks x 256 threads. ----
// Block owns 16 hidden units -> 64 gate rows {i,f,g,o}x16 = 4 MFMA m-tiles.
// Wave w owns batches [16w,16w+16). A (W_hh slice) lives in VGPRs for all 2048 steps.
__global__ __launch_bounds__(256, 1) void k_lstm(const bf16* __restrict__ Whh,
                                                 const bf16* __restrict__ xp,
                                                 bf16* h0, bf16* h1, uint32_t* flags,
                                                 float* __restrict__ out) {
    const int tid = threadIdx.x;
    const int w = tid >> 6, lane = tid & 63;
    const int l15 = lane & 15, quad = lane >> 4;
    const int u0 = blockIdx.x << 4;          // first hidden unit owned
    const int b  = (w << 4) + l15;           // batch for B-operand / outputs

    // A fragments: a[mt][kt] covers gate rows (mt*512+u0 .. +15), k = kt*32..+31
    bf16x8 a[4][16];
#pragma unroll
    for (int mt = 0; mt < 4; ++mt) {
        const bf16* wrow = Whh + (size_t)(mt * 512 + u0 + l15) * 512 + quad * 8;
#pragma unroll
        for (int kt = 0; kt < 16; ++kt) a[mt][kt] = *(const bf16x8*)(wrow + kt * 32);
    }

    float cc[4] = {0.f, 0.f, 0.f, 0.f};      // cell state: unit u0+quad*4+r, batch b

    // xp prefetch registers for the CURRENT step (loaded one step ahead)
    bf16 xn[4][4];
#pragma unroll
    for (int mt = 0; mt < 4; ++mt) {
        const bf16* xrow = xp + (size_t)(mt * 512 + u0 + (quad << 2)) * NTOT + b;  // t = 0
#pragma unroll
        for (int r = 0; r < 4; ++r) xn[mt][r] = xrow[(size_t)r * NTOT];
    }

    for (int t = 0; t < SEQN; ++t) {
        const bf16* hr = (t & 1) ? h1 : h0;
        bf16*       hw = (t & 1) ? h0 : h1;

        // B fragments: h[b][k] via relaxed agent-scope atomic loads (cache-bypass,
        // coherent against other blocks' write-through stores; no buffer_inv needed)
        bf16x8 bfr[16];
        const u64* hq = (const u64*)(hr + b * 512 + quad * 8);   // 32 bf16 = 8 u64 per kt
#pragma unroll
        for (int kt = 0; kt < 16; ++kt) {
            u64 q0 = __hip_atomic_load(hq + kt * 8,     __ATOMIC_RELAXED, __HIP_MEMORY_SCOPE_AGENT);
            u64 q1 = __hip_atomic_load(hq + kt * 8 + 1, __ATOMIC_RELAXED, __HIP_MEMORY_SCOPE_AGENT);
            union { u64 q[2]; bf16x8 v; } uu; uu.q[0] = q0; uu.q[1] = q1;
            bfr[kt] = uu.v;
        }

        // acc init = prefetched x_proj slice
        f32x4 acc[4];
#pragma unroll
        for (int mt = 0; mt < 4; ++mt) {
#pragma unroll
            for (int r = 0; r < 4; ++r) acc[mt][r] = (float)xn[mt][r];
        }

#pragma unroll
        for (int kt = 0; kt < 16; ++kt)
#pragma unroll
            for (int mt = 0; mt < 4; ++mt)
                acc[mt] = __builtin_amdgcn_mfma_f32_16x16x32_bf16(a[mt][kt], bfr[kt], acc[mt], 0, 0, 0);

        // cell update: lane holds i,f,g,o for unit u0+quad*4+r, batch b
        float hv[4];
#pragma unroll
        for (int r = 0; r < 4; ++r) {
            float iv = sigf(acc[0][r]);
            float fv = sigf(acc[1][r]);
            float gv = tanhfast(acc[2][r]);
            float ov = sigf(acc[3][r]);
            cc[r] = fv * cc[r] + iv * gv;
            hv[r] = ov * tanhfast(cc[r]);
        }

        const int u = u0 + (quad << 2);
        float4 o4 = make_float4(hv[0], hv[1], hv[2], hv[3]);
        *(float4*)(out + (size_t)t * 32768 + b * 512 + u) = o4;          // outputs[t]
        bf16x4 h4;
        h4[0] = (bf16)hv[0]; h4[1] = (bf16)hv[1]; h4[2] = (bf16)hv[2]; h4[3] = (bf16)hv[3];
        union { bf16x4 v; u64 q; } hu; hu.v = h4;
        // write-through agent-scope store: acked at coherence point (no wbl2 needed)
        __hip_atomic_store((u64*)(hw + b * 512 + u), hu.q, __ATOMIC_RELAXED, __HIP_MEMORY_SCOPE_AGENT);

        if (t == SEQN - 1) {
            *(float4*)(out + (size_t)SEQN * 32768 + b * 512 + u) = o4;   // h_n
            float4 c4 = make_float4(cc[0], cc[1], cc[2], cc[3]);
            *(float4*)(out + (size_t)SEQN * 32768 + 32768 + b * 512 + u) = c4; // c_n
        } else {
            // pin store->prefetch issue order (vmcnt retires oldest-first)
            asm volatile("" ::: "memory");
            // prefetch next step's xp BEFORE the wait: HBM latency hides under barrier
#pragma unroll
            for (int mt = 0; mt < 4; ++mt) {
                const bf16* xrow = xp + (size_t)(mt * 512 + u0 + (quad << 2)) * NTOT
                                      + (size_t)(t + 1) * 64 + b;
#pragma unroll
                for (int r = 0; r < 4; ++r) xn[mt][r] = xrow[(size_t)r * NTOT];
            }
            // drain the 2 stores (oldest), keep the 16 prefetch loads in flight
            asm volatile("s_waitcnt vmcnt(16)" ::: "memory");
            asm volatile("s_barrier" ::: "memory");      // raw: no implicit vmcnt(0)
            if (tid == 0)
                __hip_atomic_store(flags + (blockIdx.x << 3), (uint32_t)(t + 1),
                                   __ATOMIC_RELAXED, __HIP_MEMORY_SCOPE_AGENT);
            // all waves poll independently: 32 lanes read all 32 flags in one load
            const uint32_t tgt = (uint32_t)(t + 1);
            for (;;) {
                uint32_t fv = __hip_atomic_load(flags + ((lane & 31) << 3),
                                                __ATOMIC_RELAXED, __HIP_MEMORY_SCOPE_AGENT);
                if (__all((int)(fv >= tgt))) break;
                __builtin_amdgcn_s_sleep(1);
            }
            asm volatile("" ::: "memory");   // no hoisting next step's h loads above poll
        }
    }
}

extern "C" void kernel_launch(void* const* d_in, const int* in_sizes, int n_in,
                              void* d_out, int out_size, void* d_ws, size_t ws_size,
                              hipStream_t stream) {
    (void)in_sizes; (void)n_in; (void)out_size; (void)ws_size;
    const float* X   = (const float*)d_in[0];
    const float* Wih = (const float*)d_in[1];
    const float* Whh = (const float*)d_in[2];
    const float* bih = (const float*)d_in[3];
    const float* bhh = (const float*)d_in[4];
    float* out = (float*)d_out;
    char*  ws  = (char*)d_ws;

    float* bias = (float*)(ws + BIAS_OFF);
    bf16*  Wihb = (bf16*)(ws + WIH_OFF);
    bf16*  Whhb = (bf16*)(ws + WHH_OFF);
    bf16*  Xb   = (bf16*)(ws + XBF_OFF);
    bf16*  xp   = (bf16*)(ws + XP_OFF);
    bf16*  h0   = (bf16*)(ws + H0_OFF);
    bf16*  h1   = (bf16*)(ws + H1_OFF);
    uint32_t* flags = (uint32_t*)(ws + CNT_OFF);

    k_init<<<64, 256, 0, stream>>>(bih, bhh, bias, (uint32_t*)ws, (int)(BIAS_OFF / 4));
    k_cvt<<<8192, 256, 0, stream>>>(X,   Xb,   NTOT * IDIM / 4);
    k_cvt<<<1024, 256, 0, stream>>>(Wih, Wihb, GDIM * IDIM / 4);
    k_cvt<<<1024, 256, 0, stream>>>(Whh, Whhb, GDIM * HDIM / 4);
    dim3 gg(16, 1024);
    k_gemm_xproj<<<gg, 256, 0, stream>>>(Wihb, Xb, bias, xp);
    k_lstm<<<32, 256, 0, stream>>>(Whhb, xp, h0, h1, flags, out);
}